// Round 8
// baseline (81.847 us; speedup 1.0000x reference)
//
#include <hip/hip_runtime.h>
#include <math.h>

#define INVT (1.0f / 0.07f)
#define CSHIFT (1.0f / 0.07f)

using bf16x8 = __attribute__((ext_vector_type(8))) short;
using f32x4  = __attribute__((ext_vector_type(4))) float;

__device__ __forceinline__ int lower_bound_i(const int* a, int n, int v) {
    int lo = 0, hi = n;
    while (lo < hi) { int mid = (lo + hi) >> 1; if (a[mid] < v) lo = mid + 1; else hi = mid; }
    return lo;
}

__device__ __forceinline__ unsigned short f2bf(float x) {
    unsigned int u = __float_as_uint(x);
    unsigned int r = (u + 0x7fffu + ((u >> 16) & 1u)) >> 16;   // RNE
    return (unsigned short)r;
}

__device__ __forceinline__ float agent_ld(const float* p) {
    return __hip_atomic_load(p, __ATOMIC_RELAXED, __HIP_MEMORY_SCOPE_AGENT);
}

// ---------------- kernel 1: normalize + bf16 tiled convert + zero + meta ----------------
__global__ void k_prep(const float* __restrict__ fb, const float* __restrict__ fd,
                       int Nb, int Nd, int D,
                       unsigned short* __restrict__ fbt, unsigned short* __restrict__ fdt,
                       unsigned int* __restrict__ zbase, int zcount,
                       const int* __restrict__ td, const int* __restrict__ bd,
                       const int* __restrict__ im,
                       int* __restrict__ mouth_word) {
    int zidx = blockIdx.x * blockDim.x + threadIdx.x;
    if (zidx < zcount) zbase[zidx] = 0u;

    int gw = zidx >> 6;
    int lane = threadIdx.x & 63;
    int ktiles = D >> 5;
    if (gw < Nb + Nd) {
        const float* row; unsigned short* ob; int rt, r;
        if (gw < Nb) {
            row = fb + (size_t)gw * D; ob = fbt; rt = gw >> 4; r = gw & 15;
        } else {
            int j = gw - Nb;
            row = fd + (size_t)j * D; ob = fdt; rt = j >> 4; r = j & 15;
        }
        float s = 0.f;
        for (int d = lane * 4; d < D; d += 256) {
            float4 v = *(const float4*)(row + d);
            s += v.x * v.x + v.y * v.y + v.z * v.z + v.w * v.w;
        }
        #pragma unroll
        for (int m = 32; m >= 1; m >>= 1) s += __shfl_xor(s, m, 64);
        float inv = rsqrtf(s);
        for (int d = lane * 4; d < D; d += 256) {
            float4 v = *(const float4*)(row + d);
            ushort4 o;
            o.x = f2bf(v.x * inv); o.y = f2bf(v.y * inv);
            o.z = f2bf(v.z * inv); o.w = f2bf(v.w * inv);
            int kt = d >> 5, kk = d & 31;
            int slot = (kk >> 3) * 16 + r, elem = kk & 7;
            *(ushort4*)(ob + (((size_t)(rt * ktiles + kt)) << 9) + slot * 8 + elem) = o;
        }
    }
    if (blockIdx.x == 0) {
        int t = threadIdx.x;
        for (int i = t; i < Nb; i += blockDim.x) mouth_word[i] = -1;
        __syncthreads();
        for (int j = t; j < Nd; j += blockDim.x) {
            if (im[j] == 1) atomicMax(&mouth_word[bd[j]], td[j]);
        }
    }
}

// ---------------- kernel 2: templated ablation variants ----------------
// V0 = full (real).  V1 = GEMM only.  V2 = +epilogue (no global traffic).
// V3 = +global atomics & handoff (no finish).
template<int V>
__global__ __launch_bounds__(256, 4)
void k_main(const unsigned short* __restrict__ fbt, const unsigned short* __restrict__ fdt,
            const int* __restrict__ tb, const int* __restrict__ bb_arr,
            const int* __restrict__ td, const int* __restrict__ bd,
            const int* __restrict__ im, const int* __restrict__ ut,
            const int* __restrict__ mouth_word,
            int Nb, int Nd, int D, int G,
            float* __restrict__ rowpart, float* __restrict__ colpart,
            unsigned int* __restrict__ dcnt, float* __restrict__ out) {
    __shared__ float cnum[64], ct1[64], ct3[64], rsum[64];
    __shared__ int lastflag;

    int t = threadIdx.x, lane = t & 63, wid = t >> 6;
    int wr = wid >> 1, wc = wid & 1;
    int bm = blockIdx.x * 64, bn = blockIdx.y * 64;
    int l15 = lane & 15, lhi = lane >> 4;

    if (t < 64) { cnum[t] = 0.f; ct1[t] = 0.f; ct3[t] = 0.f; rsum[t] = 0.f; }

    int ktiles = D >> 5;
    const unsigned short* a0p = fbt + (((size_t)(((bm >> 4) + wr * 2) * ktiles)) << 9) + lane * 8;
    const unsigned short* a1p = a0p + ((size_t)ktiles << 9);
    const unsigned short* b0p = fdt + (((size_t)(((bn >> 4) + wc * 2) * ktiles)) << 9) + lane * 8;
    const unsigned short* b1p = b0p + ((size_t)ktiles << 9);

    f32x4 acc[2][2] = {};
    #pragma unroll 8
    for (int kt = 0; kt < ktiles; ++kt) {
        size_t o = (size_t)kt << 9;
        bf16x8 a0 = *(const bf16x8*)(a0p + o);
        bf16x8 a1 = *(const bf16x8*)(a1p + o);
        bf16x8 b0 = *(const bf16x8*)(b0p + o);
        bf16x8 b1 = *(const bf16x8*)(b1p + o);
        acc[0][0] = __builtin_amdgcn_mfma_f32_16x16x32_bf16(a0, b0, acc[0][0], 0, 0, 0);
        acc[0][1] = __builtin_amdgcn_mfma_f32_16x16x32_bf16(a0, b1, acc[0][1], 0, 0, 0);
        acc[1][0] = __builtin_amdgcn_mfma_f32_16x16x32_bf16(a1, b0, acc[1][0], 0, 0, 0);
        acc[1][1] = __builtin_amdgcn_mfma_f32_16x16x32_bf16(a1, b1, acc[1][1], 0, 0, 0);
    }

    if constexpr (V == 1) {
        float s = 0.f;
        #pragma unroll
        for (int mi = 0; mi < 2; ++mi)
            #pragma unroll
            for (int nj = 0; nj < 2; ++nj)
                #pragma unroll
                for (int r = 0; r < 4; ++r) s += acc[mi][nj][r];
        asm volatile("" :: "v"(s));   // keep GEMM live (rule #17)
        return;
    }

    // ---- epilogue ----
    int cgb[2], cgm[2], cgc[2];
    #pragma unroll
    for (int nj = 0; nj < 2; ++nj) {
        int col = bn + wc * 32 + nj * 16 + l15;
        cgb[nj] = bd[col]; cgm[nj] = im[col]; cgc[nj] = td[col];
    }

    float pnum[2] = {0.f, 0.f}, pt1[2] = {0.f, 0.f}, pt3[2] = {0.f, 0.f};
    float prow[2][4];

    #pragma unroll
    for (int mi = 0; mi < 2; ++mi) {
        #pragma unroll
        for (int r = 0; r < 4; ++r) {
            int i = bm + wr * 32 + mi * 16 + lhi * 4 + r;
            int tbi = tb[i], bbi = bb_arr[i];
            int mw = mouth_word[bbi];
            bool fg = (tbi != -1);
            float pr = 0.f;
            #pragma unroll
            for (int nj = 0; nj < 2; ++nj) {
                float e = __expf(acc[mi][nj][r] * INVT - CSHIFT);
                bool match = fg ? (cgc[nj] == mw) : ((cgb[nj] == bbi) && (cgm[nj] == 0));
                float a = (match && (bbi != cgb[nj])) ? 0.f : e;
                pnum[nj] += match ? e : 0.f;
                pt1[nj] += a;
                pt3[nj] += match ? a : 0.f;
                pr += a;
            }
            prow[mi][r] = pr;
        }
    }

    __syncthreads();

    #pragma unroll
    for (int nj = 0; nj < 2; ++nj) {
        float n = pnum[nj], x1 = pt1[nj], x3 = pt3[nj];
        n  += __shfl_xor(n, 16, 64);  n  += __shfl_xor(n, 32, 64);
        x1 += __shfl_xor(x1, 16, 64); x1 += __shfl_xor(x1, 32, 64);
        x3 += __shfl_xor(x3, 16, 64); x3 += __shfl_xor(x3, 32, 64);
        if (lhi == 0) {
            int c = wc * 32 + nj * 16 + l15;
            atomicAdd(&cnum[c], n); atomicAdd(&ct1[c], x1); atomicAdd(&ct3[c], x3);
        }
    }
    #pragma unroll
    for (int mi = 0; mi < 2; ++mi) {
        #pragma unroll
        for (int r = 0; r < 4; ++r) {
            float v = prow[mi][r];
            v += __shfl_xor(v, 1, 64); v += __shfl_xor(v, 2, 64);
            v += __shfl_xor(v, 4, 64); v += __shfl_xor(v, 8, 64);
            if (l15 == 0) atomicAdd(&rsum[wr * 32 + mi * 16 + lhi * 4 + r], v);
        }
    }
    __syncthreads();

    if constexpr (V == 2) {
        if (t < 64) {
            float z = cnum[t] + ct1[t] + ct3[t] + rsum[t];
            asm volatile("" :: "v"(z));
        }
        return;
    }

    float* cp = colpart + (size_t)(blockIdx.x & 7) * 3 * Nd;
    if (t < 64) {
        atomicAdd(&cp[bn + t], cnum[t]);
        atomicAdd(&cp[Nd + bn + t], ct1[t]);
        atomicAdd(&cp[2 * Nd + bn + t], ct3[t]);
    } else if (t < 128) {
        atomicAdd(&rowpart[(size_t)(blockIdx.y & 3) * Nb + bm + (t - 64)], rsum[t - 64]);
    }

    asm volatile("s_waitcnt vmcnt(0)" ::: "memory");
    __syncthreads();
    if (t == 0) {
        int lf = 0;
        unsigned int old = atomicAdd(&dcnt[blockIdx.x * 16], 1u);
        if (old == gridDim.y - 1) {
            unsigned int old2 = atomicAdd(&dcnt[1024], 1u);
            lf = (old2 == gridDim.x - 1) ? 1 : 0;
        }
        lastflag = lf;
    }
    __syncthreads();

    if constexpr (V == 3) return;
    if (!lastflag) return;

    // ---- last block: merge partials, t2, group reduction, loss ----
    __shared__ float t2g[1024], bgs[1024], red[256];
    for (int i = t; i < 1024; i += 256) { t2g[i] = 0.f; bgs[i] = 0.f; }
    __syncthreads();
    for (int i = t; i < Nb; i += 256) {
        float r = agent_ld(&rowpart[i]) + agent_ld(&rowpart[Nb + i])
                + agent_ld(&rowpart[2 * Nb + i]) + agent_ld(&rowpart[3 * Nb + i]);
        int tbi = tb[i], bbi = bb_arr[i] & 1023;
        if (tbi != -1) {
            int g = lower_bound_i(ut, G, mouth_word[bbi]);
            atomicAdd(&t2g[g & 1023], r);
        } else {
            atomicAdd(&bgs[bbi], r);
        }
    }
    __syncthreads();
    float acc2 = 0.f;
    for (int g = t; g < G; g += 256) {
        int s = lower_bound_i(td, Nd, ut[g]);
        int e = (g + 1 < G) ? lower_bound_i(td, Nd, ut[g + 1]) : Nd;
        float sn = 0.f, s1 = 0.f, s3 = 0.f;
        for (int c = s; c < e; ++c) {
            #pragma unroll
            for (int p = 0; p < 8; ++p) {
                const float* base = colpart + (size_t)p * 3 * Nd;
                sn += agent_ld(&base[c]);
                s1 += agent_ld(&base[Nd + c]);
                s3 += agent_ld(&base[2 * Nd + c]);
            }
        }
        int gb = bd[s], gm = im[s];
        float t2 = t2g[g & 1023];
        if (gm == 0 && gb >= 0 && gb < 1024) t2 += bgs[gb];
        acc2 += logf(s1 + t2 - s3) - logf(sn);
    }
    red[t] = acc2;
    __syncthreads();
    for (int k = 128; k >= 1; k >>= 1) {
        if (t < k) red[t] += red[t + k];
        __syncthreads();
    }
    if (t == 0) out[0] = red[0] / (float)G;
}

extern "C" void kernel_launch(void* const* d_in, const int* in_sizes, int n_in,
                              void* d_out, int out_size, void* d_ws, size_t ws_size,
                              hipStream_t stream) {
    const float* fb = (const float*)d_in[0];
    const float* fd = (const float*)d_in[1];
    const int* tb = (const int*)d_in[2];
    const int* td = (const int*)d_in[3];
    const int* bb = (const int*)d_in[4];
    const int* bd = (const int*)d_in[5];
    const int* im = (const int*)d_in[6];
    const int* ut = (const int*)d_in[7];

    int Nb = in_sizes[2];
    int Nd = in_sizes[3];
    int G  = in_sizes[7];
    int D  = in_sizes[0] / Nb;
    float* out = (float*)d_out;

    char* p = (char*)d_ws;
    unsigned short* fbt = (unsigned short*)p; p += (size_t)Nb * D * sizeof(unsigned short);
    unsigned short* fdt = (unsigned short*)p; p += (size_t)Nd * D * sizeof(unsigned short);
    // zeroed region: rowpart | colpart | dcnt | dcntB (contiguous u32s)
    float* rowpart = (float*)p;  p += (size_t)4 * Nb * sizeof(float);
    float* colpart = (float*)p;  p += (size_t)24 * Nd * sizeof(float);
    unsigned int* dcnt = (unsigned int*)p;  p += 1025 * sizeof(unsigned int);
    unsigned int* dcntB = (unsigned int*)p; p += 1025 * sizeof(unsigned int);
    int zcount = 4 * Nb + 24 * Nd + 2050;
    // non-zeroed scratch for ablation variants
    float* rowpartB = (float*)p; p += (size_t)4 * Nb * sizeof(float);
    float* colpartB = (float*)p; p += (size_t)24 * Nd * sizeof(float);
    int* mouth_word = (int*)p;   p += (size_t)Nb * sizeof(int);
    float* outB = (float*)p;     p += sizeof(float);

    {
        int waves = Nb + Nd;
        int blocks = (waves + 3) / 4;
        k_prep<<<blocks, 256, 0, stream>>>(fb, fd, Nb, Nd, D, fbt, fdt,
                                           (unsigned int*)rowpart, zcount,
                                           td, bd, im, mouth_word);
    }

    dim3 grid(Nb / 64, Nd / 64);
    // V0: real result
    k_main<0><<<grid, 256, 0, stream>>>(fbt, fdt, tb, bb, td, bd, im, ut, mouth_word,
                                        Nb, Nd, D, G, rowpart, colpart, dcnt, out);
    // Ablation probes (scratch buffers; rocprof decomposition)
    k_main<1><<<grid, 256, 0, stream>>>(fbt, fdt, tb, bb, td, bd, im, ut, mouth_word,
                                        Nb, Nd, D, G, rowpartB, colpartB, dcntB, outB);
    k_main<2><<<grid, 256, 0, stream>>>(fbt, fdt, tb, bb, td, bd, im, ut, mouth_word,
                                        Nb, Nd, D, G, rowpartB, colpartB, dcntB, outB);
    k_main<3><<<grid, 256, 0, stream>>>(fbt, fdt, tb, bb, td, bd, im, ut, mouth_word,
                                        Nb, Nd, D, G, rowpartB, colpartB, dcntB, outB);
}

// Round 9
// 44.944 us; speedup vs baseline: 1.8211x; 1.8211x over previous
//
#include <hip/hip_runtime.h>
#include <math.h>

#define INVT (1.0f / 0.07f)
#define CSHIFT (1.0f / 0.07f)

using bf16x8 = __attribute__((ext_vector_type(8))) short;
using f32x4  = __attribute__((ext_vector_type(4))) float;

__device__ __forceinline__ int lower_bound_i(const int* a, int n, int v) {
    int lo = 0, hi = n;
    while (lo < hi) { int mid = (lo + hi) >> 1; if (a[mid] < v) lo = mid + 1; else hi = mid; }
    return lo;
}

__device__ __forceinline__ unsigned short f2bf(float x) {
    unsigned int u = __float_as_uint(x);
    unsigned int r = (u + 0x7fffu + ((u >> 16) & 1u)) >> 16;   // RNE
    return (unsigned short)r;
}

__device__ __forceinline__ float agent_ld(const float* p) {
    return __hip_atomic_load(p, __ATOMIC_RELAXED, __HIP_MEMORY_SCOPE_AGENT);
}
__device__ __forceinline__ void agent_st(float* p, float v) {
    __hip_atomic_store(p, v, __ATOMIC_RELAXED, __HIP_MEMORY_SCOPE_AGENT);
}

// ---------------- kernel 1: normalize + bf16 tiled convert + zero + meta ----------------
// Tile = (16 rows x 32 k) = 512 bf16 (1KB). Slot s holds row s&15, k-chunk (s>>4)*8.
__global__ void k_prep(const float* __restrict__ fb, const float* __restrict__ fd,
                       int Nb, int Nd, int D,
                       unsigned short* __restrict__ fbt, unsigned short* __restrict__ fdt,
                       unsigned int* __restrict__ zbase, int zcount,
                       const int* __restrict__ td, const int* __restrict__ bd,
                       const int* __restrict__ im,
                       int* __restrict__ mouth_word) {
    int zidx = blockIdx.x * blockDim.x + threadIdx.x;
    if (zidx < zcount) zbase[zidx] = 0u;

    int gw = zidx >> 6;
    int lane = threadIdx.x & 63;
    int ktiles = D >> 5;
    if (gw < Nb + Nd) {
        const float* row; unsigned short* ob; int rt, r;
        if (gw < Nb) {
            row = fb + (size_t)gw * D; ob = fbt; rt = gw >> 4; r = gw & 15;
        } else {
            int j = gw - Nb;
            row = fd + (size_t)j * D; ob = fdt; rt = j >> 4; r = j & 15;
        }
        float s = 0.f;
        for (int d = lane * 4; d < D; d += 256) {
            float4 v = *(const float4*)(row + d);
            s += v.x * v.x + v.y * v.y + v.z * v.z + v.w * v.w;
        }
        #pragma unroll
        for (int m = 32; m >= 1; m >>= 1) s += __shfl_xor(s, m, 64);
        float inv = rsqrtf(s);
        for (int d = lane * 4; d < D; d += 256) {
            float4 v = *(const float4*)(row + d);
            ushort4 o;
            o.x = f2bf(v.x * inv); o.y = f2bf(v.y * inv);
            o.z = f2bf(v.z * inv); o.w = f2bf(v.w * inv);
            int kt = d >> 5, kk = d & 31;
            int slot = (kk >> 3) * 16 + r, elem = kk & 7;
            *(ushort4*)(ob + (((size_t)(rt * ktiles + kt)) << 9) + slot * 8 + elem) = o;
        }
    }
    if (blockIdx.x == 0) {
        int t = threadIdx.x;
        for (int i = t; i < Nb; i += blockDim.x) mouth_word[i] = -1;
        __syncthreads();
        for (int j = t; j < Nd; j += blockDim.x) {
            if (im[j] == 1) atomicMax(&mouth_word[bd[j]], td[j]);
        }
    }
}

// ---------------- kernel 2: MFMA GEMM + epilogue + hierarchical parallel finish ----------------
__global__ __launch_bounds__(256, 4)
void k_main(const unsigned short* __restrict__ fbt, const unsigned short* __restrict__ fdt,
            const int* __restrict__ tb, const int* __restrict__ bb_arr,
            const int* __restrict__ td, const int* __restrict__ bd,
            const int* __restrict__ im, const int* __restrict__ ut,
            const int* __restrict__ mouth_word,
            int Nb, int Nd, int D, int G,
            float* __restrict__ rowpart, float* __restrict__ colpart,
            float* __restrict__ mnum, float* __restrict__ m1, float* __restrict__ m3,
            float* __restrict__ t2g, float* __restrict__ bgs,
            unsigned int* __restrict__ rowcnt, unsigned int* __restrict__ colcnt,
            unsigned int* __restrict__ dcnt, float* __restrict__ out) {
    __shared__ float cnum[64], ct1[64], ct3[64], rsum[64];
    __shared__ int rowflag, colflag, lastflag;

    int t = threadIdx.x, lane = t & 63, wid = t >> 6;
    int wr = wid >> 1, wc = wid & 1;
    int bm = blockIdx.x * 64, bn = blockIdx.y * 64;
    int l15 = lane & 15, lhi = lane >> 4;

    if (t < 64) { cnum[t] = 0.f; ct1[t] = 0.f; ct3[t] = 0.f; rsum[t] = 0.f; }

    int ktiles = D >> 5;
    const unsigned short* a0p = fbt + (((size_t)(((bm >> 4) + wr * 2) * ktiles)) << 9) + lane * 8;
    const unsigned short* a1p = a0p + ((size_t)ktiles << 9);
    const unsigned short* b0p = fdt + (((size_t)(((bn >> 4) + wc * 2) * ktiles)) << 9) + lane * 8;
    const unsigned short* b1p = b0p + ((size_t)ktiles << 9);

    // register double-buffered GEMM loop
    f32x4 acc[2][2] = {};
    bf16x8 ca0 = *(const bf16x8*)a0p;
    bf16x8 ca1 = *(const bf16x8*)a1p;
    bf16x8 cb0 = *(const bf16x8*)b0p;
    bf16x8 cb1 = *(const bf16x8*)b1p;
    size_t o = 0;
    #pragma unroll 7
    for (int kt = 0; kt + 1 < ktiles; ++kt) {
        o += 512;
        bf16x8 na0 = *(const bf16x8*)(a0p + o);
        bf16x8 na1 = *(const bf16x8*)(a1p + o);
        bf16x8 nb0 = *(const bf16x8*)(b0p + o);
        bf16x8 nb1 = *(const bf16x8*)(b1p + o);
        acc[0][0] = __builtin_amdgcn_mfma_f32_16x16x32_bf16(ca0, cb0, acc[0][0], 0, 0, 0);
        acc[0][1] = __builtin_amdgcn_mfma_f32_16x16x32_bf16(ca0, cb1, acc[0][1], 0, 0, 0);
        acc[1][0] = __builtin_amdgcn_mfma_f32_16x16x32_bf16(ca1, cb0, acc[1][0], 0, 0, 0);
        acc[1][1] = __builtin_amdgcn_mfma_f32_16x16x32_bf16(ca1, cb1, acc[1][1], 0, 0, 0);
        ca0 = na0; ca1 = na1; cb0 = nb0; cb1 = nb1;
    }
    acc[0][0] = __builtin_amdgcn_mfma_f32_16x16x32_bf16(ca0, cb0, acc[0][0], 0, 0, 0);
    acc[0][1] = __builtin_amdgcn_mfma_f32_16x16x32_bf16(ca0, cb1, acc[0][1], 0, 0, 0);
    acc[1][0] = __builtin_amdgcn_mfma_f32_16x16x32_bf16(ca1, cb0, acc[1][0], 0, 0, 0);
    acc[1][1] = __builtin_amdgcn_mfma_f32_16x16x32_bf16(ca1, cb1, acc[1][1], 0, 0, 0);

    // ---- epilogue ----
    int cgb[2], cgm[2], cgc[2];
    #pragma unroll
    for (int nj = 0; nj < 2; ++nj) {
        int col = bn + wc * 32 + nj * 16 + l15;
        cgb[nj] = bd[col]; cgm[nj] = im[col]; cgc[nj] = td[col];
    }

    float pnum[2] = {0.f, 0.f}, pt1[2] = {0.f, 0.f}, pt3[2] = {0.f, 0.f};
    float prow[2][4];

    #pragma unroll
    for (int mi = 0; mi < 2; ++mi) {
        #pragma unroll
        for (int r = 0; r < 4; ++r) {
            int i = bm + wr * 32 + mi * 16 + lhi * 4 + r;
            int tbi = tb[i], bbi = bb_arr[i];
            int mw = mouth_word[bbi];
            bool fg = (tbi != -1);
            float pr = 0.f;
            #pragma unroll
            for (int nj = 0; nj < 2; ++nj) {
                float e = __expf(acc[mi][nj][r] * INVT - CSHIFT);
                bool match = fg ? (cgc[nj] == mw) : ((cgb[nj] == bbi) && (cgm[nj] == 0));
                float a = (match && (bbi != cgb[nj])) ? 0.f : e;
                pnum[nj] += match ? e : 0.f;
                pt1[nj] += a;
                pt3[nj] += match ? a : 0.f;
                pr += a;
            }
            prow[mi][r] = pr;
        }
    }

    __syncthreads();

    #pragma unroll
    for (int nj = 0; nj < 2; ++nj) {
        float n = pnum[nj], x1 = pt1[nj], x3 = pt3[nj];
        n  += __shfl_xor(n, 16, 64);  n  += __shfl_xor(n, 32, 64);
        x1 += __shfl_xor(x1, 16, 64); x1 += __shfl_xor(x1, 32, 64);
        x3 += __shfl_xor(x3, 16, 64); x3 += __shfl_xor(x3, 32, 64);
        if (lhi == 0) {
            int c = wc * 32 + nj * 16 + l15;
            atomicAdd(&cnum[c], n); atomicAdd(&ct1[c], x1); atomicAdd(&ct3[c], x3);
        }
    }
    #pragma unroll
    for (int mi = 0; mi < 2; ++mi) {
        #pragma unroll
        for (int r = 0; r < 4; ++r) {
            float v = prow[mi][r];
            v += __shfl_xor(v, 1, 64); v += __shfl_xor(v, 2, 64);
            v += __shfl_xor(v, 4, 64); v += __shfl_xor(v, 8, 64);
            if (l15 == 0) atomicAdd(&rsum[wr * 32 + mi * 16 + lhi * 4 + r], v);
        }
    }
    __syncthreads();

    // partitioned global accumulation
    float* cp = colpart + (size_t)(blockIdx.x & 7) * 3 * Nd;
    if (t < 64) {
        atomicAdd(&cp[bn + t], cnum[t]);
        atomicAdd(&cp[Nd + bn + t], ct1[t]);
        atomicAdd(&cp[2 * Nd + bn + t], ct3[t]);
    } else if (t < 128) {
        atomicAdd(&rowpart[(size_t)(blockIdx.y & 3) * Nb + bm + (t - 64)], rsum[t - 64]);
    }

    // ---- level-1 arrival (per-bx and per-by counters) ----
    asm volatile("s_waitcnt vmcnt(0)" ::: "memory");
    __syncthreads();
    if (t == 0) {
        rowflag = (atomicAdd(&rowcnt[blockIdx.x * 16], 1u) == gridDim.y - 1) ? 1 : 0;
        colflag = (atomicAdd(&colcnt[blockIdx.y * 16], 1u) == gridDim.x - 1) ? 1 : 0;
    }
    __syncthreads();
    int nfin = rowflag + colflag;
    if (nfin == 0) return;

    // ---- row finisher: merge rowparts for rows bm..bm+63, scatter t2 pieces ----
    if (rowflag && t < 64) {
        int i = bm + t;
        float r = agent_ld(&rowpart[i]) + agent_ld(&rowpart[Nb + i])
                + agent_ld(&rowpart[2 * Nb + i]) + agent_ld(&rowpart[3 * Nb + i]);
        int tbi = tb[i], bbi = bb_arr[i] & 1023;
        if (tbi != -1) {
            int g = lower_bound_i(ut, G, mouth_word[bbi]);
            atomicAdd(&t2g[g], r);
        } else {
            atomicAdd(&bgs[bbi], r);
        }
    }
    // ---- col finisher: merge 8 colpart partitions for cols bn..bn+63 ----
    if (colflag && t < 192) {
        int c = t / 3, arr = t - c * 3;
        int col = bn + c;
        float s0 = 0.f;
        #pragma unroll
        for (int p = 0; p < 8; ++p)
            s0 += agent_ld(&colpart[(size_t)p * 3 * Nd + (size_t)arr * Nd + col]);
        float* dst = (arr == 0 ? mnum : (arr == 1 ? m1 : m3)) + col;
        agent_st(dst, s0);
        // second chunk: cols bn+64/... no — 64 cols x 3 = 192 tasks exactly, done.
    }

    // ---- level-2 arrival ----
    asm volatile("s_waitcnt vmcnt(0)" ::: "memory");
    __syncthreads();
    if (t == 0) {
        unsigned int newv = atomicAdd(dcnt, (unsigned int)nfin) + (unsigned int)nfin;
        lastflag = (newv == gridDim.x + gridDim.y) ? 1 : 0;
    }
    __syncthreads();
    if (!lastflag) return;

    // ---- final block: group reduction + loss ----
    __shared__ float red[256];
    float acc2 = 0.f;
    for (int g = t; g < G; g += 256) {
        int s = lower_bound_i(td, Nd, ut[g]);
        int e = (g + 1 < G) ? lower_bound_i(td, Nd, ut[g + 1]) : Nd;
        float sn = 0.f, s1 = 0.f, s3 = 0.f;
        for (int c = s; c < e; ++c) {
            sn += agent_ld(&mnum[c]);
            s1 += agent_ld(&m1[c]);
            s3 += agent_ld(&m3[c]);
        }
        int gb = bd[s], gm = im[s];
        float t2 = agent_ld(&t2g[g]);
        if (gm == 0 && gb >= 0 && gb < 1024) t2 += agent_ld(&bgs[gb]);
        acc2 += logf(s1 + t2 - s3) - logf(sn);
    }
    red[t] = acc2;
    __syncthreads();
    for (int k = 128; k >= 1; k >>= 1) {
        if (t < k) red[t] += red[t + k];
        __syncthreads();
    }
    if (t == 0) out[0] = red[0] / (float)G;
}

extern "C" void kernel_launch(void* const* d_in, const int* in_sizes, int n_in,
                              void* d_out, int out_size, void* d_ws, size_t ws_size,
                              hipStream_t stream) {
    const float* fb = (const float*)d_in[0];
    const float* fd = (const float*)d_in[1];
    const int* tb = (const int*)d_in[2];
    const int* td = (const int*)d_in[3];
    const int* bb = (const int*)d_in[4];
    const int* bd = (const int*)d_in[5];
    const int* im = (const int*)d_in[6];
    const int* ut = (const int*)d_in[7];

    int Nb = in_sizes[2];
    int Nd = in_sizes[3];
    int G  = in_sizes[7];
    int D  = in_sizes[0] / Nb;
    float* out = (float*)d_out;

    char* p = (char*)d_ws;
    unsigned short* fbt = (unsigned short*)p; p += (size_t)Nb * D * sizeof(unsigned short);
    unsigned short* fdt = (unsigned short*)p; p += (size_t)Nd * D * sizeof(unsigned short);
    // ---- zeroed region (contiguous u32s) ----
    char* zstart = p;
    float* rowpart = (float*)p;  p += (size_t)4 * Nb * sizeof(float);
    float* colpart = (float*)p;  p += (size_t)24 * Nd * sizeof(float);
    float* t2g = (float*)p;      p += 1024 * sizeof(float);
    float* bgs = (float*)p;      p += 1024 * sizeof(float);
    unsigned int* rowcnt = (unsigned int*)p; p += 64 * 16 * sizeof(unsigned int);
    unsigned int* colcnt = (unsigned int*)p; p += 16 * 16 * sizeof(unsigned int);
    unsigned int* dcnt = (unsigned int*)p;   p += 16 * sizeof(unsigned int);
    int zcount = (int)((p - zstart) / 4);
    // ---- non-zeroed ----
    float* mnum = (float*)p; p += (size_t)Nd * sizeof(float);
    float* m1 = (float*)p;   p += (size_t)Nd * sizeof(float);
    float* m3 = (float*)p;   p += (size_t)Nd * sizeof(float);
    int* mouth_word = (int*)p; p += (size_t)Nb * sizeof(int);

    {
        int waves = Nb + Nd;
        int blocks = (waves + 3) / 4;
        k_prep<<<blocks, 256, 0, stream>>>(fb, fd, Nb, Nd, D, fbt, fdt,
                                           (unsigned int*)zstart, zcount,
                                           td, bd, im, mouth_word);
    }

    dim3 grid(Nb / 64, Nd / 64);
    k_main<<<grid, 256, 0, stream>>>(fbt, fdt, tb, bb, td, bd, im, ut, mouth_word,
                                     Nb, Nd, D, G,
                                     rowpart, colpart, mnum, m1, m3, t2g, bgs,
                                     rowcnt, colcnt, dcnt, out);
}